// Round 14
// baseline (131.703 us; speedup 1.0000x reference)
//
#include <hip/hip_runtime.h>
#include <hip/hip_cooperative_groups.h>

namespace cg = cooperative_groups;

#define N_TOTAL   16777216
#define NWIN      65536
#define MIN_FREQS 202
#define MIN_TIMES 51773
#define NBLK      256      /* 1 block/CU; cooperative grid */

/* workspace layout (float indices) — zero-init-free */
#define IDX_TCNT    2      /* int; zeroed by blk0 in phase 1 */
#define IDX_FMALL   3
#define IDX_INVNORM 5
#define IDX_FCNT    6
#define IDX_FMASK   8      /* 256 floats, NATURAL frequency order */
#define IDX_SLOTS   264    /* 256 rows x 256 floats, plain stores (row = block) */
#define IDX_AMAXB   65800  /* 256 per-block abs-max */
#define IDX_TMAXB   66056  /* 256 per-block time-energy max */
#define IDX_SUMSQ   66312  /* 65536 per-window time energy */
#define IDX_TMASKA  131848 /* 65536 time mask */

typedef __attribute__((ext_vector_type(8)))  short bf16x8;
typedef __attribute__((ext_vector_type(16))) float f32x16;

__device__ __forceinline__ float dpp_row_sum16(float x)
{
    x += __int_as_float(__builtin_amdgcn_mov_dpp(__float_as_int(x), 0xB1,  0xF, 0xF, true));
    x += __int_as_float(__builtin_amdgcn_mov_dpp(__float_as_int(x), 0x4E,  0xF, 0xF, true));
    x += __int_as_float(__builtin_amdgcn_mov_dpp(__float_as_int(x), 0x141, 0xF, 0xF, true));
    x += __int_as_float(__builtin_amdgcn_mov_dpp(__float_as_int(x), 0x140, 0xF, 0xF, true));
    return x;
}

__device__ __forceinline__ unsigned short bf16r(float v)   /* f32 -> bf16 RNE */
{
    unsigned u = __float_as_uint(v);
    return (unsigned short)((u + 0x7FFFu + ((u >> 16) & 1u)) >> 16);
}
__device__ __forceinline__ unsigned bfpair(float a, float b)
{
    return (unsigned)bf16r(a) | ((unsigned)bf16r(b) << 16);
}

__device__ __forceinline__ void do_stage(short (*Ab)[264], const float4 v0, const float4 v1,
                                         int wrow, int scol, float* sumsq_g,
                                         float& amax, float& tmx)
{
    amax = fmaxf(amax, fmaxf(fmaxf(fabsf(v0.x), fabsf(v0.y)),
                             fmaxf(fabsf(v0.z), fabsf(v0.w))));
    amax = fmaxf(amax, fmaxf(fmaxf(fabsf(v1.x), fabsf(v1.y)),
                             fmaxf(fabsf(v1.z), fabsf(v1.w))));
    float ss = v0.x*v0.x + v0.y*v0.y + v0.z*v0.z + v0.w*v0.w
             + v1.x*v1.x + v1.y*v1.y + v1.z*v1.z + v1.w*v1.w;
    ss = dpp_row_sum16(ss);
    ss += __shfl_xor(ss, 16);
    if (scol == 0) { sumsq_g[wrow] = ss; tmx = fmaxf(tmx, ss); }
    uint4 u;
    u.x = bfpair(v0.x, v0.y); u.y = bfpair(v0.z, v0.w);
    u.z = bfpair(v1.x, v1.y); u.w = bfpair(v1.z, v1.w);
    *(uint4*)&Ab[wrow][scol * 8] = u;
}

/* ===== single cooperative kernel: stats -> masks -> output ================ */
__global__ __launch_bounds__(1024) void k_all(const float* __restrict__ x,
                                              float* __restrict__ out,
                                              float* __restrict__ W)
{
    __shared__ short Abuf[2][32][264];
    __shared__ float red[1024];
    __shared__ float sE[512];
    __shared__ float reS[256], imS[256], twrS[128], twiS[128], fmS[256];

    const int tid  = threadIdx.x;
    const int lane = tid & 63;
    const int wv   = tid >> 6;
    const int hi   = lane >> 5;
    const int col  = lane & 31;
    const int wrow = tid >> 5;
    const int scol = tid & 31;
    const int b    = blockIdx.x;

    /* ---------------- phase 1: MFMA direct-DFT stats (r12, proven) -------- */
    bf16x8 F[16];
    {
        const int f = ((wv & 7) << 5) + col;
        const bool use_sin = (wv >= 8);
#pragma unroll
        for (int kc = 0; kc < 16; ++kc) {
            bf16x8 t;
#pragma unroll
            for (int j = 0; j < 8; ++j) {
                const int n = kc * 16 + hi * 8 + j;
                const int m = (n * f) & 255;
                float s, c;
                __sincosf((float)m * 0.024543692606170f, &s, &c);
                t[j] = (short)bf16r(use_sin ? s : c);
            }
            F[kc] = t;
        }
    }

    const float* xb = x + ((size_t)b << 16);
    float* sumsq = W + IDX_SUMSQ + (b << 8);
    float amax = 0.f, tmx = 0.f, fsum = 0.f;

    float4 v0, v1;
    {
        const float4* p = (const float4*)(xb + tid * 8);
        v0 = p[0]; v1 = p[1];
    }
    do_stage(Abuf[0], v0, v1, wrow, scol, sumsq, amax, tmx);
    __syncthreads();

    int cur = 0;
#pragma unroll 1
    for (int g = 0; g < 8; ++g) {
        if (g < 7) {
            const float4* p = (const float4*)(xb + (g + 1) * 8192 + tid * 8);
            v0 = p[0]; v1 = p[1];
        }
        f32x16 acc;
#pragma unroll
        for (int r = 0; r < 16; ++r) acc[r] = 0.f;
#pragma unroll
        for (int kc = 0; kc < 16; ++kc) {
            const bf16x8 af = *(const bf16x8*)&Abuf[cur][col][kc * 16 + hi * 8];
            acc = __builtin_amdgcn_mfma_f32_32x32x16_bf16(af, F[kc], acc, 0, 0, 0);
        }
#pragma unroll
        for (int r = 0; r < 16; ++r) fsum += acc[r] * acc[r];
        if (g < 7)
            do_stage(Abuf[cur ^ 1], v0, v1, wrow, scol, sumsq + (g + 1) * 32, amax, tmx);
        __syncthreads();
        cur ^= 1;
    }

    fsum += __shfl_xor(fsum, 32);
    if (lane < 32)
        sE[((wv >= 8) ? 256 : 0) + ((wv & 7) << 5) + col] = fsum;
    __syncthreads();
    if (tid < 256)
        W[IDX_SLOTS + (size_t)b * 256 + tid] = sE[tid] + sE[256 + tid];
    if (b == 0 && tid == 0) ((int*)W)[IDX_TCNT] = 0;

    red[tid] = amax; __syncthreads();
    for (int s = 512; s > 0; s >>= 1) {
        if (tid < s) red[tid] = fmaxf(red[tid], red[tid + s]);
        __syncthreads();
    }
    if (tid == 0) W[IDX_AMAXB + b] = red[0];
    __syncthreads();
    red[tid] = tmx; __syncthreads();
    for (int s = 512; s > 0; s >>= 1) {
        if (tid < s) red[tid] = fmaxf(red[tid], red[tid + s]);
        __syncthreads();
    }
    if (tid == 0) W[IDX_TMAXB + b] = red[0];

    cg::this_grid().sync();

    /* ---------------- phase 2: masks ---------------- */
    /* all blocks: tthr from TMAXB, tmask for own 256 windows + TCNT */
    red[tid] = (tid < 256) ? W[IDX_TMAXB + tid] : 0.f;
    __syncthreads();
    for (int s = 128; s > 0; s >>= 1) {
        if (tid < s) red[tid] = fmaxf(red[tid], red[tid + s]);
        __syncthreads();
    }
    const float tthr = 0.05f * red[0];
    __syncthreads();
    int mm = 0;
    if (tid < 256) {
        const int i = (b << 8) + tid;
        mm = (W[IDX_SUMSQ + i] > tthr) ? 1 : 0;
        W[IDX_TMASKA + i] = (float)mm;
    }
    red[tid] = (float)mm; __syncthreads();
    for (int s = 512; s > 0; s >>= 1) {
        if (tid < s) red[tid] += red[tid + s];
        __syncthreads();
    }
    if (tid == 0) atomicAdd((int*)W + IDX_TCNT, (int)red[0]);

    if (b == 0) {
        /* amax -> invnorm */
        red[tid] = (tid < 256) ? W[IDX_AMAXB + tid] : 0.f;
        __syncthreads();
        for (int s = 128; s > 0; s >>= 1) {
            if (tid < s) red[tid] = fmaxf(red[tid], red[tid + s]);
            __syncthreads();
        }
        const float amax_g = red[0];
        __syncthreads();
        /* freq energy: sum 256 slot rows, 4 row-slabs in parallel */
        float acc = 0.f;
        for (int s = (tid >> 8); s < NBLK; s += 4)
            acc += W[IDX_SLOTS + (size_t)s * 256 + (tid & 255)];
        if (tid < 512) sE[tid] = 0.f;
        __syncthreads();
        atomicAdd(&sE[tid & 255], acc);
        __syncthreads();
        red[tid] = (tid < 256) ? sE[tid] : 0.f;
        __syncthreads();
        for (int s = 128; s > 0; s >>= 1) {
            if (tid < s) red[tid] = fmaxf(red[tid], red[tid + s]);
            __syncthreads();
        }
        const float fthr = 0.05f * red[0];
        __syncthreads();
        const int my = (tid < 256 && sE[tid] > fthr) ? 1 : 0;
        red[tid] = (float)my; __syncthreads();
        for (int s = 512; s > 0; s >>= 1) {
            if (tid < s) red[tid] += red[tid + s];
            __syncthreads();
        }
        const int fcnt = (int)red[0];
        __syncthreads();
        float m = 0.f;
        if (tid < 256) {
            if (fcnt >= MIN_FREQS) {
                m = (float)my;
            } else {
                int rank = 0;
                for (int j = 0; j < 256; j++) {
                    const float ej = sE[j];
                    if (ej > sE[tid] || (ej == sE[tid] && j < tid)) rank++;
                }
                m = (rank < MIN_FREQS) ? 1.f : 0.f;
            }
            W[IDX_FMASK + tid] = m;
        }
        red[tid] = m; __syncthreads();
        for (int s = 512; s > 0; s >>= 1) {
            if (tid < s) red[tid] += red[tid + s];
            __syncthreads();
        }
        if (tid == 0) {
            ((int*)W)[IDX_FMALL] = ((int)red[0] == 256) ? 1 : 0;
            ((int*)W)[IDX_FCNT]  = fcnt;
            W[IDX_INVNORM] = 1.f / ((amax_g > 1e-10f) ? amax_g : 1.f);
        }
    }

    cg::this_grid().sync();

    /* ---------------- phase 3a: time top-k fallback (uniform branch) ------ */
    const int tcnt = ((const int*)W)[IDX_TCNT];
    if (tcnt < MIN_TIMES) {            /* grid-uniform -> inner sync is safe */
        if (tid < 256) {
            const int t = (b << 8) + tid;
            const float st = W[IDX_SUMSQ + t];
            int rank = 0;
            for (int j = 0; j < NWIN; j++) {
                const float sj = W[IDX_SUMSQ + j];
                if (sj > st || (sj == st && j < t)) rank++;
            }
            W[IDX_TMASKA + t] = (rank < MIN_TIMES) ? 1.f : 0.f;
        }
        cg::this_grid().sync();
    }

    /* ---------------- phase 3b: output ------------------------------------ */
    const int fm_all = ((const int*)W)[IDX_FMALL];
    const float inv_norm = W[IDX_INVNORM];
    if (fm_all) {
        /* ifft(fft(x) * 1) == x : masked scaled copy, full grid width */
        const float4* xi = (const float4*)x;
        float4* yo = (float4*)out;
        const float* tmask = W + IDX_TMASKA;
#pragma unroll 4
        for (int i = b * 1024 + tid; i < N_TOTAL / 4; i += NBLK * 1024) {
            const float s = inv_norm * tmask[i >> 6];
            float4 v = xi[i];
            v.x *= s; v.y *= s; v.z *= s; v.w *= s;
            yo[i] = v;
        }
        return;
    }
    /* general path (correctness; not taken for this input): exact FFT ->
       mask -> IFFT, tid<256 active, barriers block-wide */
    if (tid < 128) {
        float s, c;
        __sincosf(-6.283185307179586f * (float)tid / 256.0f, &s, &c);
        twrS[tid] = c; twiS[tid] = s;
    }
    if (tid < 256)
        fmS[tid] = W[IDX_FMASK + (int)(__brev((unsigned)tid) >> 24)];
    __syncthreads();
    const float scale = inv_norm * (1.f / 256.f);
    for (int w = b; w < NWIN; w += NBLK) {
        const float tm = W[IDX_TMASKA + w];
        if (tm == 0.f) {
            if (tid < 256) out[w * 256 + tid] = 0.f;
            continue;
        }
        if (tid < 256) { reS[tid] = x[w * 256 + tid]; imS[tid] = 0.f; }
        __syncthreads();
        for (int lh = 7; lh >= 0; lh--) {
            const int half = 1 << lh;
            if (tid < 128) {
                const int k  = tid & (half - 1);
                const int i0 = ((tid & ~(half - 1)) << 1) | k;
                const int i1 = i0 + half;
                const float ar = reS[i0], ai = imS[i0], br = reS[i1], bi = imS[i1];
                const float dr = ar - br, di = ai - bi;
                reS[i0] = ar + br; imS[i0] = ai + bi;
                const int ti = k << (7 - lh);
                const float wr = twrS[ti], wi = twiS[ti];
                reS[i1] = dr * wr - di * wi;
                imS[i1] = dr * wi + di * wr;
            }
            __syncthreads();
        }
        if (tid < 256) { reS[tid] *= fmS[tid]; imS[tid] *= fmS[tid]; }
        __syncthreads();
        for (int lh = 0; lh < 8; lh++) {
            const int half = 1 << lh;
            if (tid < 128) {
                const int k  = tid & (half - 1);
                const int i0 = ((tid & ~(half - 1)) << 1) | k;
                const int i1 = i0 + half;
                const int ti = k << (7 - lh);
                const float wr = twrS[ti], wi = -twiS[ti];
                const float br = reS[i1], bi = imS[i1];
                const float tr = br * wr - bi * wi;
                const float ts = br * wi + bi * wr;
                const float ar = reS[i0], ai = imS[i0];
                reS[i1] = ar - tr; imS[i1] = ai - ts;
                reS[i0] = ar + tr; imS[i0] = ai + ts;
            }
            __syncthreads();
        }
        if (tid < 256) out[w * 256 + tid] = reS[tid] * scale;
        __syncthreads();
    }
}

extern "C" void kernel_launch(void* const* d_in, const int* in_sizes, int n_in,
                              void* d_out, int out_size, void* d_ws, size_t ws_size,
                              hipStream_t stream)
{
    const float* x = (const float*)d_in[0];
    float* out = (float*)d_out;
    float* W = (float*)d_ws;
    void* args[] = { (void*)&x, (void*)&out, (void*)&W };
    hipLaunchCooperativeKernel((const void*)k_all, dim3(NBLK), dim3(1024),
                               args, 0, stream);
}

// Round 15
// 89.031 us; speedup vs baseline: 1.4793x; 1.4793x over previous
//
#include <hip/hip_runtime.h>

#define N_TOTAL   16777216
#define NWIN      65536
#define MIN_FREQS 202
#define MIN_TIMES 51773
#define NBLK      256      /* k_stats grid: 1 block/CU, 256 windows each */

/* workspace layout (float indices) — zero-init-free */
#define IDX_TCNT    2      /* int; zeroed by k_stats blk0 */
#define IDX_FMALL   3
#define IDX_INVNORM 5
#define IDX_FCNT    6
#define IDX_FMASK   8      /* 256 floats, NATURAL frequency order */
#define IDX_SLOTS   264    /* 256 rows x 256 floats, PLAIN stores (row = block) */
#define IDX_AMAXB   65800  /* 256 per-block abs-max */
#define IDX_TMAXB   66056  /* 256 per-block time-energy max */
#define IDX_SUMSQ   66312  /* 65536 per-window time energy (sum x^2) */
#define IDX_TMASKA  131848 /* 65536 time mask */

typedef __attribute__((ext_vector_type(8)))  short bf16x8;
typedef __attribute__((ext_vector_type(16))) float f32x16;

__device__ __forceinline__ float dpp_row_sum16(float x)
{
    x += __int_as_float(__builtin_amdgcn_mov_dpp(__float_as_int(x), 0xB1,  0xF, 0xF, true));
    x += __int_as_float(__builtin_amdgcn_mov_dpp(__float_as_int(x), 0x4E,  0xF, 0xF, true));
    x += __int_as_float(__builtin_amdgcn_mov_dpp(__float_as_int(x), 0x141, 0xF, 0xF, true));
    x += __int_as_float(__builtin_amdgcn_mov_dpp(__float_as_int(x), 0x140, 0xF, 0xF, true));
    return x;
}

__device__ __forceinline__ unsigned short bf16r(float v)   /* f32 -> bf16 RNE */
{
    unsigned u = __float_as_uint(v);
    return (unsigned short)((u + 0x7FFFu + ((u >> 16) & 1u)) >> 16);
}
__device__ __forceinline__ unsigned bfpair(float a, float b)
{
    return (unsigned)bf16r(a) | ((unsigned)bf16r(b) << 16);
}

/* stats + f32->bf16 convert + LDS store for one thread's 8 samples */
__device__ __forceinline__ void do_stage(short (*Ab)[264], const float4 v0, const float4 v1,
                                         int wrow, int scol, float* sumsq_g,
                                         float& amax, float& tmx)
{
    amax = fmaxf(amax, fmaxf(fmaxf(fabsf(v0.x), fabsf(v0.y)),
                             fmaxf(fabsf(v0.z), fabsf(v0.w))));
    amax = fmaxf(amax, fmaxf(fmaxf(fabsf(v1.x), fabsf(v1.y)),
                             fmaxf(fabsf(v1.z), fabsf(v1.w))));
    float ss = v0.x*v0.x + v0.y*v0.y + v0.z*v0.z + v0.w*v0.w
             + v1.x*v1.x + v1.y*v1.y + v1.z*v1.z + v1.w*v1.w;
    ss = dpp_row_sum16(ss);
    ss += __shfl_xor(ss, 16);            /* 32 threads of a window -> full sum */
    if (scol == 0) { sumsq_g[wrow] = ss; tmx = fmaxf(tmx, ss); }
    uint4 u;
    u.x = bfpair(v0.x, v0.y); u.y = bfpair(v0.z, v0.w);
    u.z = bfpair(v1.x, v1.y); u.w = bfpair(v1.z, v1.w);
    *(uint4*)&Ab[wrow][scol * 8] = u;
}

/* ---- K1: MFMA direct-DFT (r12 proven) + LDS trig table for F build ------- */
__global__ __launch_bounds__(1024) void k_stats(const float* __restrict__ x,
                                                float* __restrict__ W)
{
    __shared__ short Abuf[2][32][264];   /* 2 x 16.5KB */
    __shared__ float red[1024];
    __shared__ float sE[512];
    __shared__ float ctab[256], stab[256];
    const int tid  = threadIdx.x;
    const int lane = tid & 63;
    const int wv   = tid >> 6;          /* 0..15 */
    const int hi   = lane >> 5;
    const int col  = lane & 31;
    const int wrow = tid >> 5;          /* staging: window row 0..31 */
    const int scol = tid & 31;          /* staging: 8-sample block 0..31 */

    /* trig table: 256 sincos per BLOCK (was 128 per THREAD) */
    if (tid < 256) {
        float s, c;
        __sincosf((float)tid * 0.024543692606170f, &s, &c);
        ctab[tid] = c; stab[tid] = s;
    }
    __syncthreads();

    /* F fragments: F[n][fcol] with n = 16*kc + 8*hi + j ; 64 VGPRs */
    bf16x8 F[16];
    {
        const int f = ((wv & 7) << 5) + col;
        const bool use_sin = (wv >= 8);
        const float* tab = use_sin ? stab : ctab;
#pragma unroll
        for (int kc = 0; kc < 16; ++kc) {
            bf16x8 t;
#pragma unroll
            for (int j = 0; j < 8; ++j) {
                const int n = kc * 16 + hi * 8 + j;
                t[j] = (short)bf16r(tab[(n * f) & 255]);
            }
            F[kc] = t;
        }
    }

    const int b = blockIdx.x;
    const float* xb = x + ((size_t)b << 16);       /* block's 256 windows */
    float* sumsq = W + IDX_SUMSQ + (b << 8);
    float amax = 0.f, tmx = 0.f, fsum = 0.f;

    /* prologue: load + stage wgroup 0 */
    float4 v0, v1;
    {
        const float4* p = (const float4*)(xb + tid * 8);
        v0 = p[0]; v1 = p[1];
    }
    do_stage(Abuf[0], v0, v1, wrow, scol, sumsq, amax, tmx);
    __syncthreads();

    int cur = 0;
#pragma unroll 1
    for (int g = 0; g < 8; ++g) {
        if (g < 7) {                      /* prefetch next wgroup under MFMA */
            const float4* p = (const float4*)(xb + (g + 1) * 8192 + tid * 8);
            v0 = p[0]; v1 = p[1];
        }
        f32x16 acc;
#pragma unroll
        for (int r = 0; r < 16; ++r) acc[r] = 0.f;
#pragma unroll
        for (int kc = 0; kc < 16; ++kc) {
            const bf16x8 af = *(const bf16x8*)&Abuf[cur][col][kc * 16 + hi * 8];
            acc = __builtin_amdgcn_mfma_f32_32x32x16_bf16(af, F[kc], acc, 0, 0, 0);
        }
#pragma unroll
        for (int r = 0; r < 16; ++r) fsum += acc[r] * acc[r];
        if (g < 7)
            do_stage(Abuf[cur ^ 1], v0, v1, wrow, scol, sumsq + (g + 1) * 32, amax, tmx);
        __syncthreads();
        cur ^= 1;
    }

    /* freq-energy: rows combine (lane halves), cos+sin combine in LDS,
       then PLAIN store of this block's 256-float slot row */
    fsum += __shfl_xor(fsum, 32);
    if (lane < 32)
        sE[((wv >= 8) ? 256 : 0) + ((wv & 7) << 5) + col] = fsum;
    __syncthreads();
    if (tid < 256)
        W[IDX_SLOTS + (size_t)b * 256 + tid] = sE[tid] + sE[256 + tid];
    if (b == 0 && tid == 0) ((int*)W)[IDX_TCNT] = 0;   /* runs before k_post */

    /* block tree-reduce amax / tmx -> plain per-block stores */
    red[tid] = amax; __syncthreads();
    for (int s = 512; s > 0; s >>= 1) {
        if (tid < s) red[tid] = fmaxf(red[tid], red[tid + s]);
        __syncthreads();
    }
    if (tid == 0) W[IDX_AMAXB + b] = red[0];
    __syncthreads();
    red[tid] = tmx; __syncthreads();
    for (int s = 512; s > 0; s >>= 1) {
        if (tid < s) red[tid] = fmaxf(red[tid], red[tid + s]);
        __syncthreads();
    }
    if (tid == 0) W[IDX_TMAXB + b] = red[0];
}

/* ---------------- K2: merged masks pass (1024 threads) ---------------------
   block 0      : freq mask + flags + invnorm (4-slab parallel slot sum)
   blocks 1..64 : time threshold mask + count, 1024 windows each ------------ */
__global__ __launch_bounds__(1024) void k_post(float* __restrict__ W)
{
    __shared__ float red[1024];
    __shared__ float sE[256];
    const int tid = threadIdx.x;

    if (blockIdx.x != 0) {
        /* tthr from TMAXB */
        red[tid] = (tid < 256) ? W[IDX_TMAXB + tid] : 0.f;
        __syncthreads();
        for (int s = 128; s > 0; s >>= 1) {
            if (tid < s) red[tid] = fmaxf(red[tid], red[tid + s]);
            __syncthreads();
        }
        const float tthr = 0.05f * red[0];
        __syncthreads();
        const int i = (blockIdx.x - 1) * 1024 + tid;
        const int mm = (W[IDX_SUMSQ + i] > tthr) ? 1 : 0;
        W[IDX_TMASKA + i] = (float)mm;
        red[tid] = (float)mm; __syncthreads();
        for (int s = 512; s > 0; s >>= 1) {
            if (tid < s) red[tid] += red[tid + s];
            __syncthreads();
        }
        if (tid == 0) atomicAdd((int*)W + IDX_TCNT, (int)red[0]);
        return;
    }

    /* ---- block 0: freq mask / flags / norm ---- */
    red[tid] = (tid < 256) ? W[IDX_AMAXB + tid] : 0.f;
    __syncthreads();
    for (int s = 128; s > 0; s >>= 1) {
        if (tid < s) red[tid] = fmaxf(red[tid], red[tid + s]);
        __syncthreads();
    }
    const float amax = red[0];
    __syncthreads();

    /* slot-row sum, 4 row-slabs in parallel (verified r14 phase 2) */
    float acc = 0.f;
    for (int s = (tid >> 8); s < NBLK; s += 4)
        acc += W[IDX_SLOTS + (size_t)s * 256 + (tid & 255)];
    if (tid < 256) sE[tid] = 0.f;
    __syncthreads();
    atomicAdd(&sE[tid & 255], acc);
    __syncthreads();
    red[tid] = (tid < 256) ? sE[tid] : 0.f;
    __syncthreads();
    for (int s = 128; s > 0; s >>= 1) {
        if (tid < s) red[tid] = fmaxf(red[tid], red[tid + s]);
        __syncthreads();
    }
    const float fthr = 0.05f * red[0];
    __syncthreads();
    const int my = (tid < 256 && sE[tid] > fthr) ? 1 : 0;
    red[tid] = (float)my; __syncthreads();
    for (int s = 512; s > 0; s >>= 1) {
        if (tid < s) red[tid] += red[tid + s];
        __syncthreads();
    }
    const int fcnt = (int)red[0];
    __syncthreads();
    float m = 0.f;
    if (tid < 256) {
        if (fcnt >= MIN_FREQS) {
            m = (float)my;
        } else {
            /* exact top-k; NATURAL order, ties by lower index */
            int rank = 0;
            for (int j = 0; j < 256; j++) {
                const float ej = sE[j];
                if (ej > sE[tid] || (ej == sE[tid] && j < tid)) rank++;
            }
            m = (rank < MIN_FREQS) ? 1.f : 0.f;
        }
        W[IDX_FMASK + tid] = m;
    }
    red[tid] = m; __syncthreads();
    for (int s = 512; s > 0; s >>= 1) {
        if (tid < s) red[tid] += red[tid + s];
        __syncthreads();
    }
    if (tid == 0) {
        ((int*)W)[IDX_FMALL] = ((int)red[0] == 256) ? 1 : 0;
        ((int*)W)[IDX_FCNT]  = fcnt;
        W[IDX_INVNORM] = 1.f / ((amax > 1e-10f) ? amax : 1.f);
    }
}

/* ---------------- K2b: exact time top-k fallback (early-exit normally) ----- */
__global__ __launch_bounds__(256) void k_timefb(float* __restrict__ W)
{
    if (((const int*)W)[IDX_TCNT] >= MIN_TIMES) return;
    const int t = blockIdx.x * 256 + threadIdx.x;
    const float* sumsq = W + IDX_SUMSQ;
    const float st = sumsq[t];
    int rank = 0;
    for (int j = 0; j < NWIN; j++) {
        const float sj = sumsq[j];
        if (sj > st || (sj == st && j < t)) rank++;
    }
    W[IDX_TMASKA + t] = (rank < MIN_TIMES) ? 1.f : 0.f;
}

/* ---------------- K3: output pass ------------------------------------------ */
__global__ __launch_bounds__(256) void k_out(const float* __restrict__ x,
                                             float* __restrict__ out,
                                             const float* __restrict__ W)
{
    const int tid = threadIdx.x;
    const int fm_all = ((const int*)W)[IDX_FMALL];
    const float inv_norm = W[IDX_INVNORM];
    if (fm_all) {
        /* ifft(fft(x) * 1) == x : masked scaled copy, float4 */
        const float4* xi = (const float4*)x;
        float4* yo = (float4*)out;
        const float* tmask = W + IDX_TMASKA;
        for (int i = blockIdx.x * 256 + tid; i < N_TOTAL / 4; i += gridDim.x * 256) {
            const float s = inv_norm * tmask[i >> 6];
            float4 v = xi[i];
            v.x *= s; v.y *= s; v.z *= s; v.w *= s;
            yo[i] = v;
        }
        return;
    }
    /* general path: exact FFT -> mask -> IFFT (mask lookup brev for DIF order) */
    __shared__ float re[256], im[256], twr[128], twi[128], fm[256];
    if (tid < 128) {
        float s, c;
        __sincosf(-6.283185307179586f * (float)tid / 256.0f, &s, &c);
        twr[tid] = c; twi[tid] = s;
    }
    fm[tid] = W[IDX_FMASK + (int)(__brev((unsigned)tid) >> 24)];
    __syncthreads();
    const float scale = inv_norm * (1.f / 256.f);
    for (int w = blockIdx.x; w < NWIN; w += gridDim.x) {
        const float tm = W[IDX_TMASKA + w];
        if (tm == 0.f) { out[w * 256 + tid] = 0.f; continue; }
        re[tid] = x[w * 256 + tid]; im[tid] = 0.f;
        __syncthreads();
        for (int lh = 7; lh >= 0; lh--) {
            const int half = 1 << lh;
            if (tid < 128) {
                const int k  = tid & (half - 1);
                const int i0 = ((tid & ~(half - 1)) << 1) | k;
                const int i1 = i0 + half;
                const float ar = re[i0], ai = im[i0], br = re[i1], bi = im[i1];
                const float dr = ar - br, di = ai - bi;
                re[i0] = ar + br; im[i0] = ai + bi;
                const int ti = k << (7 - lh);
                const float wr = twr[ti], wi = twi[ti];
                re[i1] = dr * wr - di * wi;
                im[i1] = dr * wi + di * wr;
            }
            __syncthreads();
        }
        re[tid] *= fm[tid]; im[tid] *= fm[tid];
        __syncthreads();
        for (int lh = 0; lh < 8; lh++) {
            const int half = 1 << lh;
            if (tid < 128) {
                const int k  = tid & (half - 1);
                const int i0 = ((tid & ~(half - 1)) << 1) | k;
                const int i1 = i0 + half;
                const int ti = k << (7 - lh);
                const float wr = twr[ti], wi = -twi[ti];
                const float br = re[i1], bi = im[i1];
                const float tr = br * wr - bi * wi;
                const float ts = br * wi + bi * wr;
                const float ar = re[i0], ai = im[i0];
                re[i1] = ar - tr; im[i1] = ai - ts;
                re[i0] = ar + tr; im[i0] = ai + ts;
            }
            __syncthreads();
        }
        out[w * 256 + tid] = re[tid] * scale;
        __syncthreads();
    }
}

extern "C" void kernel_launch(void* const* d_in, const int* in_sizes, int n_in,
                              void* d_out, int out_size, void* d_ws, size_t ws_size,
                              hipStream_t stream)
{
    const float* x = (const float*)d_in[0];
    float* out = (float*)d_out;
    float* W = (float*)d_ws;
    /* zero-init-free pipeline (plain-store slots; TCNT zeroed by k_stats) */
    hipLaunchKernelGGL(k_stats,  dim3(NBLK), dim3(1024), 0, stream, x, W);
    hipLaunchKernelGGL(k_post,   dim3(65),   dim3(1024), 0, stream, W);
    hipLaunchKernelGGL(k_timefb, dim3(256),  dim3(256),  0, stream, W);
    hipLaunchKernelGGL(k_out,    dim3(2048), dim3(256),  0, stream, x, out, W);
}

// Round 16
// 80.363 us; speedup vs baseline: 1.6389x; 1.1079x over previous
//
#include <hip/hip_runtime.h>

#define N_TOTAL   16777216
#define NWIN      65536
#define MIN_FREQS 202
#define MIN_TIMES 51773
#define NBLK      256      /* k_stats grid: 1 block/CU, 256 windows each */

/* workspace layout (float indices) — zero-init-free */
#define IDX_TCNT    2      /* int; zeroed by k_stats blk0 */
#define IDX_FMALL   3
#define IDX_INVNORM 5
#define IDX_FCNT    6
#define IDX_FMASK   8      /* 256 floats, NATURAL frequency order */
#define IDX_SLOTS   264    /* 256 rows x 256 floats, PLAIN stores (row = block) */
#define IDX_AMAXB   65800  /* 256 per-block abs-max */
#define IDX_TMAXB   66056  /* 256 per-block time-energy max */
#define IDX_SUMSQ   66312  /* 65536 per-window time energy (sum x^2) */
#define IDX_TMASKA  131848 /* 65536 time mask */

typedef __attribute__((ext_vector_type(8)))  short bf16x8;
typedef __attribute__((ext_vector_type(16))) float f32x16;

__device__ __forceinline__ float dpp_row_sum16(float x)
{
    x += __int_as_float(__builtin_amdgcn_mov_dpp(__float_as_int(x), 0xB1,  0xF, 0xF, true));
    x += __int_as_float(__builtin_amdgcn_mov_dpp(__float_as_int(x), 0x4E,  0xF, 0xF, true));
    x += __int_as_float(__builtin_amdgcn_mov_dpp(__float_as_int(x), 0x141, 0xF, 0xF, true));
    x += __int_as_float(__builtin_amdgcn_mov_dpp(__float_as_int(x), 0x140, 0xF, 0xF, true));
    return x;
}

__device__ __forceinline__ unsigned short bf16r(float v)   /* f32 -> bf16 RNE */
{
    unsigned u = __float_as_uint(v);
    return (unsigned short)((u + 0x7FFFu + ((u >> 16) & 1u)) >> 16);
}
__device__ __forceinline__ unsigned bfpair(float a, float b)
{
    return (unsigned)bf16r(a) | ((unsigned)bf16r(b) << 16);
}

/* stats + f32->bf16 convert + LDS store for one thread's 8 samples */
__device__ __forceinline__ void do_stage(short (*Ab)[264], const float4 v0, const float4 v1,
                                         int wrow, int scol, float* sumsq_g,
                                         float& amax, float& tmx)
{
    amax = fmaxf(amax, fmaxf(fmaxf(fabsf(v0.x), fabsf(v0.y)),
                             fmaxf(fabsf(v0.z), fabsf(v0.w))));
    amax = fmaxf(amax, fmaxf(fmaxf(fabsf(v1.x), fabsf(v1.y)),
                             fmaxf(fabsf(v1.z), fabsf(v1.w))));
    float ss = v0.x*v0.x + v0.y*v0.y + v0.z*v0.z + v0.w*v0.w
             + v1.x*v1.x + v1.y*v1.y + v1.z*v1.z + v1.w*v1.w;
    ss = dpp_row_sum16(ss);
    ss += __shfl_xor(ss, 16);            /* 32 threads of a window -> full sum */
    if (scol == 0) { sumsq_g[wrow] = ss; tmx = fmaxf(tmx, ss); }
    uint4 u;
    u.x = bfpair(v0.x, v0.y); u.y = bfpair(v0.z, v0.w);
    u.z = bfpair(v1.x, v1.y); u.w = bfpair(v1.z, v1.w);
    *(uint4*)&Ab[wrow][scol * 8] = u;
}

/* ---- K1: MFMA direct-DFT — EXACT r12/r13 body (sincos F build; that build
   compiled without spill: r13 arithmetic shows k_stats ~32us. r15's LDS trig
   table flipped the allocator to VGPR=64 -> 42MB scratch spill. Reverted.) -- */
__global__ __launch_bounds__(1024) void k_stats(const float* __restrict__ x,
                                                float* __restrict__ W)
{
    __shared__ short Abuf[2][32][264];   /* 2 x 16.5KB */
    __shared__ float red[1024];
    __shared__ float sE[512];
    const int tid  = threadIdx.x;
    const int lane = tid & 63;
    const int wv   = tid >> 6;          /* 0..15 */
    const int hi   = lane >> 5;
    const int col  = lane & 31;
    const int wrow = tid >> 5;          /* staging: window row 0..31 */
    const int scol = tid & 31;          /* staging: 8-sample block 0..31 */

    /* F fragments: F[n][fcol] with n = 16*kc + 8*hi + j ; 64 VGPRs */
    bf16x8 F[16];
    {
        const int f = ((wv & 7) << 5) + col;
        const bool use_sin = (wv >= 8);
#pragma unroll
        for (int kc = 0; kc < 16; ++kc) {
            bf16x8 t;
#pragma unroll
            for (int j = 0; j < 8; ++j) {
                const int n = kc * 16 + hi * 8 + j;
                const int m = (n * f) & 255;
                float s, c;
                __sincosf((float)m * 0.024543692606170f, &s, &c);
                t[j] = (short)bf16r(use_sin ? s : c);
            }
            F[kc] = t;
        }
    }

    const int b = blockIdx.x;
    const float* xb = x + ((size_t)b << 16);       /* block's 256 windows */
    float* sumsq = W + IDX_SUMSQ + (b << 8);
    float amax = 0.f, tmx = 0.f, fsum = 0.f;

    /* prologue: load + stage wgroup 0 */
    float4 v0, v1;
    {
        const float4* p = (const float4*)(xb + tid * 8);
        v0 = p[0]; v1 = p[1];
    }
    do_stage(Abuf[0], v0, v1, wrow, scol, sumsq, amax, tmx);
    __syncthreads();

    int cur = 0;
#pragma unroll 1
    for (int g = 0; g < 8; ++g) {
        if (g < 7) {                      /* prefetch next wgroup under MFMA */
            const float4* p = (const float4*)(xb + (g + 1) * 8192 + tid * 8);
            v0 = p[0]; v1 = p[1];
        }
        f32x16 acc;
#pragma unroll
        for (int r = 0; r < 16; ++r) acc[r] = 0.f;
#pragma unroll
        for (int kc = 0; kc < 16; ++kc) {
            const bf16x8 af = *(const bf16x8*)&Abuf[cur][col][kc * 16 + hi * 8];
            acc = __builtin_amdgcn_mfma_f32_32x32x16_bf16(af, F[kc], acc, 0, 0, 0);
        }
#pragma unroll
        for (int r = 0; r < 16; ++r) fsum += acc[r] * acc[r];
        if (g < 7)
            do_stage(Abuf[cur ^ 1], v0, v1, wrow, scol, sumsq + (g + 1) * 32, amax, tmx);
        __syncthreads();
        cur ^= 1;
    }

    /* freq-energy: rows combine (lane halves), cos+sin combine in LDS,
       then PLAIN store of this block's 256-float slot row */
    fsum += __shfl_xor(fsum, 32);
    if (lane < 32)
        sE[((wv >= 8) ? 256 : 0) + ((wv & 7) << 5) + col] = fsum;
    __syncthreads();
    if (tid < 256)
        W[IDX_SLOTS + (size_t)b * 256 + tid] = sE[tid] + sE[256 + tid];
    if (b == 0 && tid == 0) ((int*)W)[IDX_TCNT] = 0;   /* runs before k_post */

    /* block tree-reduce amax / tmx -> plain per-block stores */
    red[tid] = amax; __syncthreads();
    for (int s = 512; s > 0; s >>= 1) {
        if (tid < s) red[tid] = fmaxf(red[tid], red[tid + s]);
        __syncthreads();
    }
    if (tid == 0) W[IDX_AMAXB + b] = red[0];
    __syncthreads();
    red[tid] = tmx; __syncthreads();
    for (int s = 512; s > 0; s >>= 1) {
        if (tid < s) red[tid] = fmaxf(red[tid], red[tid + s]);
        __syncthreads();
    }
    if (tid == 0) W[IDX_TMAXB + b] = red[0];
}

/* ---------------- K2: merged masks pass (1024 threads, r15-verified) -------
   block 0      : freq mask + flags + invnorm (4-slab parallel slot sum)
   blocks 1..64 : time threshold mask + count, 1024 windows each ------------ */
__global__ __launch_bounds__(1024) void k_post(float* __restrict__ W)
{
    __shared__ float red[1024];
    __shared__ float sE[256];
    const int tid = threadIdx.x;

    if (blockIdx.x != 0) {
        /* tthr from TMAXB */
        red[tid] = (tid < 256) ? W[IDX_TMAXB + tid] : 0.f;
        __syncthreads();
        for (int s = 128; s > 0; s >>= 1) {
            if (tid < s) red[tid] = fmaxf(red[tid], red[tid + s]);
            __syncthreads();
        }
        const float tthr = 0.05f * red[0];
        __syncthreads();
        const int i = (blockIdx.x - 1) * 1024 + tid;
        const int mm = (W[IDX_SUMSQ + i] > tthr) ? 1 : 0;
        W[IDX_TMASKA + i] = (float)mm;
        red[tid] = (float)mm; __syncthreads();
        for (int s = 512; s > 0; s >>= 1) {
            if (tid < s) red[tid] += red[tid + s];
            __syncthreads();
        }
        if (tid == 0) atomicAdd((int*)W + IDX_TCNT, (int)red[0]);
        return;
    }

    /* ---- block 0: freq mask / flags / norm ---- */
    red[tid] = (tid < 256) ? W[IDX_AMAXB + tid] : 0.f;
    __syncthreads();
    for (int s = 128; s > 0; s >>= 1) {
        if (tid < s) red[tid] = fmaxf(red[tid], red[tid + s]);
        __syncthreads();
    }
    const float amax = red[0];
    __syncthreads();

    /* slot-row sum, 4 row-slabs in parallel (verified r14/r15) */
    float acc = 0.f;
    for (int s = (tid >> 8); s < NBLK; s += 4)
        acc += W[IDX_SLOTS + (size_t)s * 256 + (tid & 255)];
    if (tid < 256) sE[tid] = 0.f;
    __syncthreads();
    atomicAdd(&sE[tid & 255], acc);
    __syncthreads();
    red[tid] = (tid < 256) ? sE[tid] : 0.f;
    __syncthreads();
    for (int s = 128; s > 0; s >>= 1) {
        if (tid < s) red[tid] = fmaxf(red[tid], red[tid + s]);
        __syncthreads();
    }
    const float fthr = 0.05f * red[0];
    __syncthreads();
    const int my = (tid < 256 && sE[tid] > fthr) ? 1 : 0;
    red[tid] = (float)my; __syncthreads();
    for (int s = 512; s > 0; s >>= 1) {
        if (tid < s) red[tid] += red[tid + s];
        __syncthreads();
    }
    const int fcnt = (int)red[0];
    __syncthreads();
    float m = 0.f;
    if (tid < 256) {
        if (fcnt >= MIN_FREQS) {
            m = (float)my;
        } else {
            /* exact top-k; NATURAL order, ties by lower index */
            int rank = 0;
            for (int j = 0; j < 256; j++) {
                const float ej = sE[j];
                if (ej > sE[tid] || (ej == sE[tid] && j < tid)) rank++;
            }
            m = (rank < MIN_FREQS) ? 1.f : 0.f;
        }
        W[IDX_FMASK + tid] = m;
    }
    red[tid] = m; __syncthreads();
    for (int s = 512; s > 0; s >>= 1) {
        if (tid < s) red[tid] += red[tid + s];
        __syncthreads();
    }
    if (tid == 0) {
        ((int*)W)[IDX_FMALL] = ((int)red[0] == 256) ? 1 : 0;
        ((int*)W)[IDX_FCNT]  = fcnt;
        W[IDX_INVNORM] = 1.f / ((amax > 1e-10f) ? amax : 1.f);
    }
}

/* ---------------- K2b: exact time top-k fallback (early-exit normally) ----- */
__global__ __launch_bounds__(256) void k_timefb(float* __restrict__ W)
{
    if (((const int*)W)[IDX_TCNT] >= MIN_TIMES) return;
    const int t = blockIdx.x * 256 + threadIdx.x;
    const float* sumsq = W + IDX_SUMSQ;
    const float st = sumsq[t];
    int rank = 0;
    for (int j = 0; j < NWIN; j++) {
        const float sj = sumsq[j];
        if (sj > st || (sj == st && j < t)) rank++;
    }
    W[IDX_TMASKA + t] = (rank < MIN_TIMES) ? 1.f : 0.f;
}

/* ---------------- K3: output pass ------------------------------------------ */
__global__ __launch_bounds__(256) void k_out(const float* __restrict__ x,
                                             float* __restrict__ out,
                                             const float* __restrict__ W)
{
    const int tid = threadIdx.x;
    const int fm_all = ((const int*)W)[IDX_FMALL];
    const float inv_norm = W[IDX_INVNORM];
    if (fm_all) {
        /* ifft(fft(x) * 1) == x : masked scaled copy, float4 */
        const float4* xi = (const float4*)x;
        float4* yo = (float4*)out;
        const float* tmask = W + IDX_TMASKA;
        for (int i = blockIdx.x * 256 + tid; i < N_TOTAL / 4; i += gridDim.x * 256) {
            const float s = inv_norm * tmask[i >> 6];
            float4 v = xi[i];
            v.x *= s; v.y *= s; v.z *= s; v.w *= s;
            yo[i] = v;
        }
        return;
    }
    /* general path: exact FFT -> mask -> IFFT (mask lookup brev for DIF order) */
    __shared__ float re[256], im[256], twr[128], twi[128], fm[256];
    if (tid < 128) {
        float s, c;
        __sincosf(-6.283185307179586f * (float)tid / 256.0f, &s, &c);
        twr[tid] = c; twi[tid] = s;
    }
    fm[tid] = W[IDX_FMASK + (int)(__brev((unsigned)tid) >> 24)];
    __syncthreads();
    const float scale = inv_norm * (1.f / 256.f);
    for (int w = blockIdx.x; w < NWIN; w += gridDim.x) {
        const float tm = W[IDX_TMASKA + w];
        if (tm == 0.f) { out[w * 256 + tid] = 0.f; continue; }
        re[tid] = x[w * 256 + tid]; im[tid] = 0.f;
        __syncthreads();
        for (int lh = 7; lh >= 0; lh--) {
            const int half = 1 << lh;
            if (tid < 128) {
                const int k  = tid & (half - 1);
                const int i0 = ((tid & ~(half - 1)) << 1) | k;
                const int i1 = i0 + half;
                const float ar = re[i0], ai = im[i0], br = re[i1], bi = im[i1];
                const float dr = ar - br, di = ai - bi;
                re[i0] = ar + br; im[i0] = ai + bi;
                const int ti = k << (7 - lh);
                const float wr = twr[ti], wi = twi[ti];
                re[i1] = dr * wr - di * wi;
                im[i1] = dr * wi + di * wr;
            }
            __syncthreads();
        }
        re[tid] *= fm[tid]; im[tid] *= fm[tid];
        __syncthreads();
        for (int lh = 0; lh < 8; lh++) {
            const int half = 1 << lh;
            if (tid < 128) {
                const int k  = tid & (half - 1);
                const int i0 = ((tid & ~(half - 1)) << 1) | k;
                const int i1 = i0 + half;
                const int ti = k << (7 - lh);
                const float wr = twr[ti], wi = -twi[ti];
                const float br = re[i1], bi = im[i1];
                const float tr = br * wr - bi * wi;
                const float ts = br * wi + bi * wr;
                const float ar = re[i0], ai = im[i0];
                re[i1] = ar - tr; im[i1] = ai - ts;
                re[i0] = ar + tr; im[i0] = ai + ts;
            }
            __syncthreads();
        }
        out[w * 256 + tid] = re[tid] * scale;
        __syncthreads();
    }
}

extern "C" void kernel_launch(void* const* d_in, const int* in_sizes, int n_in,
                              void* d_out, int out_size, void* d_ws, size_t ws_size,
                              hipStream_t stream)
{
    const float* x = (const float*)d_in[0];
    float* out = (float*)d_out;
    float* W = (float*)d_ws;
    /* zero-init-free pipeline (plain-store slots; TCNT zeroed by k_stats) */
    hipLaunchKernelGGL(k_stats,  dim3(NBLK), dim3(1024), 0, stream, x, W);
    hipLaunchKernelGGL(k_post,   dim3(65),   dim3(1024), 0, stream, W);
    hipLaunchKernelGGL(k_timefb, dim3(256),  dim3(256),  0, stream, W);
    hipLaunchKernelGGL(k_out,    dim3(2048), dim3(256),  0, stream, x, out, W);
}

// Round 17
// 67.880 us; speedup vs baseline: 1.9402x; 1.1839x over previous
//
#include <hip/hip_runtime.h>

#define N_TOTAL   16777216
#define NWIN      65536
#define MIN_FREQS 202
#define MIN_TIMES 51773
#define NSLOTS    64
#define NBLK      256      /* k_stats grid: 1 block/CU, 256 windows each */

/* workspace layout (float indices) */
#define IDX_TCNT    2
#define IDX_FMALL   3
#define IDX_TTHR    4
#define IDX_INVNORM 5
#define IDX_FCNT    6
#define IDX_FMASK   8      /* 256 floats, NATURAL frequency order */
#define IDX_SLOTS   264    /* 64*256 floats, freq-energy partial slots */
#define IDX_AMAXB   16648  /* per-block abs-max (plain stores) */
#define IDX_TMAXB   18696  /* per-block time-energy max */
#define IDX_SUMSQ   20744  /* 65536 per-window time energy (sum x^2) */
#define IDX_TMASKA  86280  /* 65536 time mask */

typedef __attribute__((ext_vector_type(8)))  short bf16x8;
typedef __attribute__((ext_vector_type(16))) float f32x16;

__device__ __forceinline__ float dpp_row_sum16(float x)
{
    x += __int_as_float(__builtin_amdgcn_mov_dpp(__float_as_int(x), 0xB1,  0xF, 0xF, true));
    x += __int_as_float(__builtin_amdgcn_mov_dpp(__float_as_int(x), 0x4E,  0xF, 0xF, true));
    x += __int_as_float(__builtin_amdgcn_mov_dpp(__float_as_int(x), 0x141, 0xF, 0xF, true));
    x += __int_as_float(__builtin_amdgcn_mov_dpp(__float_as_int(x), 0x140, 0xF, 0xF, true));
    return x;
}

__device__ __forceinline__ unsigned short bf16r(float v)   /* f32 -> bf16 RNE */
{
    unsigned u = __float_as_uint(v);
    return (unsigned short)((u + 0x7FFFu + ((u >> 16) & 1u)) >> 16);
}
__device__ __forceinline__ unsigned bfpair(float a, float b)
{
    return (unsigned)bf16r(a) | ((unsigned)bf16r(b) << 16);
}

/* stats + f32->bf16 convert + LDS store for one thread's 8 samples */
__device__ __forceinline__ void do_stage(short (*Ab)[264], const float4 v0, const float4 v1,
                                         int wrow, int scol, float* sumsq_g,
                                         float& amax, float& tmx)
{
    amax = fmaxf(amax, fmaxf(fmaxf(fabsf(v0.x), fabsf(v0.y)),
                             fmaxf(fabsf(v0.z), fabsf(v0.w))));
    amax = fmaxf(amax, fmaxf(fmaxf(fabsf(v1.x), fabsf(v1.y)),
                             fmaxf(fabsf(v1.z), fabsf(v1.w))));
    float ss = v0.x*v0.x + v0.y*v0.y + v0.z*v0.z + v0.w*v0.w
             + v1.x*v1.x + v1.y*v1.y + v1.z*v1.z + v1.w*v1.w;
    ss = dpp_row_sum16(ss);
    ss += __shfl_xor(ss, 16);            /* 32 threads of a window -> full sum */
    if (scol == 0) { sumsq_g[wrow] = ss; tmx = fmaxf(tmx, ss); }
    uint4 u;
    u.x = bfpair(v0.x, v0.y); u.y = bfpair(v0.z, v0.w);
    u.z = bfpair(v1.x, v1.y); u.w = bfpair(v1.z, v1.w);
    *(uint4*)&Ab[wrow][scol * 8] = u;
}

/* ---- K1: MFMA direct-DFT. Y = A*F (cos|sin), col-sumsq fused in regs. -----
   16 waves/block; wave wv owns 32 f-cols (cos if wv<8 else sin, f=32*(wv&7)+c).
   A: 32-window groups staged f32->bf16 in LDS [32][264] (row pad -> b128-optimal).
   A-frag (mfma 32x32x16 A op): lane l -> row l&31, k = 8*(l>>5)+j.
   B-frag = F in 64 VGPRs, computed once per lane via sincos.
   C/D (m74/m101): col=lane&31, rows split over regs+lane-half -> column sumsq
   = per-lane reg-sum + shfl_xor(32). Time stats exact f32 during staging. ---- */
__global__ __launch_bounds__(1024) void k_stats(const float* __restrict__ x,
                                                float* __restrict__ W)
{
    __shared__ short Abuf[2][32][264];   /* 2 x 16.5KB */
    __shared__ float red[1024];
    const int tid  = threadIdx.x;
    const int lane = tid & 63;
    const int wv   = tid >> 6;          /* 0..15 */
    const int hi   = lane >> 5;
    const int col  = lane & 31;
    const int wrow = tid >> 5;          /* staging: window row 0..31 */
    const int scol = tid & 31;          /* staging: 8-sample block 0..31 */

    /* F fragments: F[n][fcol] with n = 16*kc + 8*hi + j ; 64 VGPRs */
    bf16x8 F[16];
    {
        const int f = ((wv & 7) << 5) + col;
        const bool use_sin = (wv >= 8);
#pragma unroll
        for (int kc = 0; kc < 16; ++kc) {
            bf16x8 t;
#pragma unroll
            for (int j = 0; j < 8; ++j) {
                const int n = kc * 16 + hi * 8 + j;
                const int m = (n * f) & 255;
                float s, c;
                __sincosf((float)m * 0.024543692606170f, &s, &c);
                t[j] = (short)bf16r(use_sin ? s : c);
            }
            F[kc] = t;
        }
    }

    const int b = blockIdx.x;
    const float* xb = x + ((size_t)b << 16);       /* block's 256 windows */
    float* sumsq = W + IDX_SUMSQ + (b << 8);
    float amax = 0.f, tmx = 0.f, fsum = 0.f;

    /* prologue: load + stage wgroup 0 */
    float4 v0, v1;
    {
        const float4* p = (const float4*)(xb + tid * 8);
        v0 = p[0]; v1 = p[1];
    }
    do_stage(Abuf[0], v0, v1, wrow, scol, sumsq, amax, tmx);
    __syncthreads();

    int cur = 0;
#pragma unroll 1
    for (int g = 0; g < 8; ++g) {
        if (g < 7) {                      /* prefetch next wgroup under MFMA */
            const float4* p = (const float4*)(xb + (g + 1) * 8192 + tid * 8);
            v0 = p[0]; v1 = p[1];
        }
        f32x16 acc;
#pragma unroll
        for (int r = 0; r < 16; ++r) acc[r] = 0.f;
#pragma unroll
        for (int kc = 0; kc < 16; ++kc) {
            const bf16x8 af = *(const bf16x8*)&Abuf[cur][col][kc * 16 + hi * 8];
            acc = __builtin_amdgcn_mfma_f32_32x32x16_bf16(af, F[kc], acc, 0, 0, 0);
        }
#pragma unroll
        for (int r = 0; r < 16; ++r) fsum += acc[r] * acc[r];
        if (g < 7)
            do_stage(Abuf[cur ^ 1], v0, v1, wrow, scol, sumsq + (g + 1) * 32, amax, tmx);
        __syncthreads();
        cur ^= 1;
    }

    /* freq-energy: combine lane halves (rows), add to distributed slots */
    fsum += __shfl_xor(fsum, 32);
    if (lane < 32)
        atomicAdd(&W[IDX_SLOTS + (size_t)(b & (NSLOTS - 1)) * 256 + ((wv & 7) << 5) + lane],
                  fsum);

    /* block tree-reduce amax / tmx -> plain per-block stores */
    red[tid] = amax; __syncthreads();
    for (int s = 512; s > 0; s >>= 1) {
        if (tid < s) red[tid] = fmaxf(red[tid], red[tid + s]);
        __syncthreads();
    }
    if (tid == 0) W[IDX_AMAXB + b] = red[0];
    __syncthreads();
    red[tid] = tmx; __syncthreads();
    for (int s = 512; s > 0; s >>= 1) {
        if (tid < s) red[tid] = fmaxf(red[tid], red[tid + s]);
        __syncthreads();
    }
    if (tid == 0) W[IDX_TMAXB + b] = red[0];
}

/* ---------------- K2: merged masks pass ------------------------------------ */
__global__ __launch_bounds__(256) void k_post(float* __restrict__ W)
{
    __shared__ float red[256];
    const int tid = threadIdx.x;

    if (blockIdx.x != 0) {
        float tm = 0.f;
#pragma unroll
        for (int k = 0; k < ((NBLK + 255) / 256); ++k)
            tm = fmaxf(tm, W[IDX_TMAXB + k * 256 + tid]);
        red[tid] = tm; __syncthreads();
        for (int s = 128; s > 0; s >>= 1) {
            if (tid < s) red[tid] = fmaxf(red[tid], red[tid + s]);
            __syncthreads();
        }
        const float tthr = 0.05f * red[0];
        __syncthreads();
        const float* sumsq = W + IDX_SUMSQ;
        float* tmask = W + IDX_TMASKA;
        const int base = (blockIdx.x - 1) * 1024 + tid;
        int c = 0;
#pragma unroll
        for (int k = 0; k < 4; k++) {
            const int i = base + k * 256;
            const int mm = (sumsq[i] > tthr) ? 1 : 0;
            c += mm;
            tmask[i] = (float)mm;
        }
        red[tid] = (float)c; __syncthreads();
        for (int s = 128; s > 0; s >>= 1) {
            if (tid < s) red[tid] += red[tid + s];
            __syncthreads();
        }
        if (tid == 0) atomicAdd((int*)W + IDX_TCNT, (int)red[0]);
        return;
    }

    __shared__ float e[256];
    float am = 0.f;
#pragma unroll
    for (int k = 0; k < ((NBLK + 255) / 256); ++k)
        am = fmaxf(am, W[IDX_AMAXB + k * 256 + tid]);
    red[tid] = am; __syncthreads();
    for (int s = 128; s > 0; s >>= 1) {
        if (tid < s) red[tid] = fmaxf(red[tid], red[tid + s]);
        __syncthreads();
    }
    const float amax = red[0];
    __syncthreads();

    float acc = 0.f;
#pragma unroll
    for (int s = 0; s < NSLOTS; s++) acc += W[IDX_SLOTS + s * 256 + tid];
    e[tid] = acc;
    red[tid] = acc; __syncthreads();
    for (int s = 128; s > 0; s >>= 1) {
        if (tid < s) red[tid] = fmaxf(red[tid], red[tid + s]);
        __syncthreads();
    }
    const float fthr = 0.05f * red[0];
    __syncthreads();
    const int my = (acc > fthr) ? 1 : 0;
    red[tid] = (float)my; __syncthreads();
    for (int s = 128; s > 0; s >>= 1) {
        if (tid < s) red[tid] += red[tid + s];
        __syncthreads();
    }
    const int fcnt = (int)red[0];
    __syncthreads();
    float m;
    if (fcnt >= MIN_FREQS) {
        m = (float)my;
    } else {
        int rank = 0;
        for (int j = 0; j < 256; j++) {
            const float ej = e[j];
            if (ej > acc || (ej == acc && j < tid)) rank++;
        }
        m = (rank < MIN_FREQS) ? 1.f : 0.f;
    }
    W[IDX_FMASK + tid] = m;
    red[tid] = m; __syncthreads();
    for (int s = 128; s > 0; s >>= 1) {
        if (tid < s) red[tid] += red[tid + s];
        __syncthreads();
    }
    if (tid == 0) {
        ((int*)W)[IDX_FMALL] = ((int)red[0] == 256) ? 1 : 0;
        ((int*)W)[IDX_FCNT]  = fcnt;
        W[IDX_INVNORM] = 1.f / ((amax > 1e-10f) ? amax : 1.f);
    }
}

/* ---------------- K2b: exact time top-k fallback (early-exit normally) ----- */
__global__ __launch_bounds__(256) void k_timefb(float* __restrict__ W)
{
    if (((const int*)W)[IDX_TCNT] >= MIN_TIMES) return;
    const int t = blockIdx.x * 256 + threadIdx.x;
    const float* sumsq = W + IDX_SUMSQ;
    const float st = sumsq[t];
    int rank = 0;
    for (int j = 0; j < NWIN; j++) {
        const float sj = sumsq[j];
        if (sj > st || (sj == st && j < t)) rank++;
    }
    W[IDX_TMASKA + t] = (rank < MIN_TIMES) ? 1.f : 0.f;
}

/* ---------------- K3: output pass ------------------------------------------ */
__global__ __launch_bounds__(256) void k_out(const float* __restrict__ x,
                                             float* __restrict__ out,
                                             const float* __restrict__ W)
{
    const int tid = threadIdx.x;
    const int fm_all = ((const int*)W)[IDX_FMALL];
    const float inv_norm = W[IDX_INVNORM];
    if (fm_all) {
        const float4* xi = (const float4*)x;
        float4* yo = (float4*)out;
        const float* tmask = W + IDX_TMASKA;
        for (int i = blockIdx.x * 256 + tid; i < N_TOTAL / 4; i += gridDim.x * 256) {
            const float s = inv_norm * tmask[i >> 6];
            float4 v = xi[i];
            v.x *= s; v.y *= s; v.z *= s; v.w *= s;
            yo[i] = v;
        }
        return;
    }
    /* general path: exact FFT -> mask -> IFFT (mask lookup brev for DIF order) */
    __shared__ float re[256], im[256], twr[128], twi[128], fm[256];
    if (tid < 128) {
        float s, c;
        __sincosf(-6.283185307179586f * (float)tid / 256.0f, &s, &c);
        twr[tid] = c; twi[tid] = s;
    }
    fm[tid] = W[IDX_FMASK + (int)(__brev((unsigned)tid) >> 24)];
    __syncthreads();
    const float scale = inv_norm * (1.f / 256.f);
    for (int w = blockIdx.x; w < NWIN; w += gridDim.x) {
        const float tm = W[IDX_TMASKA + w];
        if (tm == 0.f) { out[w * 256 + tid] = 0.f; continue; }
        re[tid] = x[w * 256 + tid]; im[tid] = 0.f;
        __syncthreads();
        for (int lh = 7; lh >= 0; lh--) {
            const int half = 1 << lh;
            if (tid < 128) {
                const int k  = tid & (half - 1);
                const int i0 = ((tid & ~(half - 1)) << 1) | k;
                const int i1 = i0 + half;
                const float ar = re[i0], ai = im[i0], br = re[i1], bi = im[i1];
                const float dr = ar - br, di = ai - bi;
                re[i0] = ar + br; im[i0] = ai + bi;
                const int ti = k << (7 - lh);
                const float wr = twr[ti], wi = twi[ti];
                re[i1] = dr * wr - di * wi;
                im[i1] = dr * wi + di * wr;
            }
            __syncthreads();
        }
        re[tid] *= fm[tid]; im[tid] *= fm[tid];
        __syncthreads();
        for (int lh = 0; lh < 8; lh++) {
            const int half = 1 << lh;
            if (tid < 128) {
                const int k  = tid & (half - 1);
                const int i0 = ((tid & ~(half - 1)) << 1) | k;
                const int i1 = i0 + half;
                const int ti = k << (7 - lh);
                const float wr = twr[ti], wi = -twi[ti];
                const float br = re[i1], bi = im[i1];
                const float tr = br * wr - bi * wi;
                const float ts = br * wi + bi * wr;
                const float ar = re[i0], ai = im[i0];
                re[i1] = ar - tr; im[i1] = ai - ts;
                re[i0] = ar + tr; im[i0] = ai + ts;
            }
            __syncthreads();
        }
        out[w * 256 + tid] = re[tid] * scale;
        __syncthreads();
    }
}

extern "C" void kernel_launch(void* const* d_in, const int* in_sizes, int n_in,
                              void* d_out, int out_size, void* d_ws, size_t ws_size,
                              hipStream_t stream)
{
    const float* x = (const float*)d_in[0];
    float* out = (float*)d_out;
    float* W = (float*)d_ws;
    hipMemsetAsync(d_ws, 0, (size_t)IDX_AMAXB * sizeof(float), stream);
    hipLaunchKernelGGL(k_stats,  dim3(NBLK), dim3(1024), 0, stream, x, W);
    hipLaunchKernelGGL(k_post,   dim3(65),   dim3(256),  0, stream, W);
    hipLaunchKernelGGL(k_timefb, dim3(256),  dim3(256),  0, stream, W);
    hipLaunchKernelGGL(k_out,    dim3(2048), dim3(256),  0, stream, x, out, W);
}